// Round 4
// baseline (820.740 us; speedup 1.0000x reference)
//
#include <hip/hip_runtime.h>
#include <stdint.h>
#include <stddef.h>

typedef _Float16 f16;
typedef _Float16 f16x8 __attribute__((ext_vector_type(8)));
typedef _Float16 f16x4 __attribute__((ext_vector_type(4)));
typedef float f32x4 __attribute__((ext_vector_type(4)));

#define NB 8192
#define DK 256

// ---------- DPP xor-add reduction over 16-lane groups (VALU pipe, keeps LDS pipe free) ----------
// ctrl must be an integer constant expression -> template parameter.
template<int CTRL>
__device__ __forceinline__ float dpp_add(float x) {
  int yi = __builtin_amdgcn_mov_dpp(__float_as_int(x), CTRL, 0xF, 0xF, true);
  return x + __int_as_float(yi);
}
__device__ __forceinline__ float reduce16(float x) {
  x = dpp_add<0xB1>(x);   // quad_perm [1,0,3,2]  : pairs
  x = dpp_add<0x4E>(x);   // quad_perm [2,3,0,1]  : quads
  x = dpp_add<0x141>(x);  // row_half_mirror      : cross-quad (8)
  x = dpp_add<0x140>(x);  // row_mirror           : cross-octet (16)
  return x;
}

// ---------- prep: L2-normalize rows, fold in 1/sqrt(temperature), convert to fp16 ----------
__global__ __launch_bounds__(256) void prep_kernel(const float* __restrict__ f_img,
                                                   const float* __restrict__ f_txt,
                                                   f16* __restrict__ fi16,
                                                   f16* __restrict__ ft16) {
  const int wave = threadIdx.x >> 6, lane = threadIdx.x & 63;
  const int row = blockIdx.x * 4 + wave;              // 0..16383
  const float* src = (row < NB) ? f_img : f_txt;
  f16* dst = (row < NB) ? fi16 : ft16;
  const int r = row & (NB - 1);
  const float4 v = *reinterpret_cast<const float4*>(src + (size_t)r * DK + lane * 4);
  float ss = v.x * v.x + v.y * v.y + v.z * v.z + v.w * v.w;
  #pragma unroll
  for (int d = 1; d < 64; d <<= 1) ss += __shfl_xor(ss, d, 64);
  // scale = (1/||x||) * 1/sqrt(0.07)  so that fp16 dot == logits (temperature folded in)
  const float sc = 3.7796447300922722f / sqrtf(ss);
  f16x4 o;
  o[0] = (f16)(v.x * sc); o[1] = (f16)(v.y * sc);
  o[2] = (f16)(v.z * sc); o[3] = (f16)(v.w * sc);
  *reinterpret_cast<f16x4*>(dst + (size_t)r * DK + lane * 4) = o;
}

// ---------- main tile kernel: both matmuls + masked row-indexed accumulation ----------
// Tile (rt,ct): T1[i][j] = fi[row0+i]·ft[col0+j]   (i2t logits)
//              T2'[i][j] = ft[row0+i]·fi[col0+j]   (t2i logits, transposed view)
// All accumulations are indexed by global row rg and masked by scores[rg][cg] —
// scores is read streaming (nontemporal), exactly once per pass, never transposed.
template<int PASS>
__global__ __launch_bounds__(256, 2) void hloss_tile(
    const f16* __restrict__ fi16, const f16* __restrict__ ft16,
    const float* __restrict__ scores,
    float* __restrict__ s_row, float* __restrict__ s_col,
    float* __restrict__ cnt_neg, float* __restrict__ cnt_pos,
    const float* __restrict__ nl_row, const float* __restrict__ nl_col,
    float* __restrict__ acc_i2t, float* __restrict__ acc_t2i)
{
  __shared__ __align__(16) char smem[65536];   // 4 panels of [128][64] fp16 (16 KiB each)
  const int bid = blockIdx.x;
  const int swz = (bid & 7) * 512 + (bid >> 3);     // bijective XCD swizzle (grid = 4096)
  const int rt = swz >> 6, ct = swz & 63;
  const int row0 = rt << 7, col0 = ct << 7;
  const int tid = threadIdx.x;
  const int wave = tid >> 6, lane = tid & 63;
  const int wr = wave >> 1, wc = wave & 1;          // 2x2 waves over 128x128, 64x64 each

  f32x4 acc1[4][4], acc2[4][4];
  #pragma unroll
  for (int m = 0; m < 4; ++m)
    #pragma unroll
    for (int n = 0; n < 4; ++n) {
      acc1[m][n] = {0.f, 0.f, 0.f, 0.f};
      acc2[m][n] = {0.f, 0.f, 0.f, 0.f};
    }

  // Staging: wave w fills panel w. Panels: 0=fi[row0] (A1), 1=ft[col0] (B1), 2=ft[row0] (A2), 3=fi[col0] (B2).
  const f16* psrc = (wave == 0) ? (fi16 + (size_t)row0 * DK)
                  : (wave == 1) ? (ft16 + (size_t)col0 * DK)
                  : (wave == 2) ? (ft16 + (size_t)row0 * DK)
                                : (fi16 + (size_t)col0 * DK);
  char* const pbase = smem + (wave << 14);
  const int sub = lane >> 3;                      // row within 8-row group
  const int sslot = ((lane & 7) ^ sub) << 4;      // pre-swizzled source slot (LDS dest stays linear: both-sides rule)

  const int fr = lane & 15;                       // frag row / col lane
  const int fg = lane >> 4;                       // k-group
  const int rswz = (fr & 7) << 4;                 // read-side XOR swizzle (panel row ≡ fr mod 8)

  for (int kt = 0; kt < 4; ++kt) {                // K = 256 in 4 chunks of BK=64
    __syncthreads();
    #pragma unroll
    for (int i = 0; i < 16; ++i) {                // 16 x 1KiB = one 16 KiB panel per wave
      const char* g = (const char*)psrc + (((i << 3) + sub) << 9) + (kt << 7) + sslot;
      __builtin_amdgcn_global_load_lds(
          (const __attribute__((address_space(1))) uint32_t*)g,
          (__attribute__((address_space(3))) uint32_t*)(pbase + (i << 10)),
          16, 0, 0);
    }
    __syncthreads();
    #pragma unroll
    for (int ks = 0; ks < 2; ++ks) {
      const int koff = ((ks << 6) + (fg << 4)) ^ rswz;
      {
        f16x8 a[4], b[4];
        #pragma unroll
        for (int m = 0; m < 4; ++m) {
          a[m] = *reinterpret_cast<const f16x8*>(smem + (((wr << 6) + (m << 4) + fr) << 7) + koff);
          b[m] = *reinterpret_cast<const f16x8*>(smem + 16384 + (((wc << 6) + (m << 4) + fr) << 7) + koff);
        }
        #pragma unroll
        for (int m = 0; m < 4; ++m)
          #pragma unroll
          for (int n = 0; n < 4; ++n)
            acc1[m][n] = __builtin_amdgcn_mfma_f32_16x16x32_f16(a[m], b[n], acc1[m][n], 0, 0, 0);
      }
      {
        f16x8 a[4], b[4];
        #pragma unroll
        for (int m = 0; m < 4; ++m) {
          a[m] = *reinterpret_cast<const f16x8*>(smem + 32768 + (((wr << 6) + (m << 4) + fr) << 7) + koff);
          b[m] = *reinterpret_cast<const f16x8*>(smem + 49152 + (((wc << 6) + (m << 4) + fr) << 7) + koff);
        }
        #pragma unroll
        for (int m = 0; m < 4; ++m)
          #pragma unroll
          for (int n = 0; n < 4; ++n)
            acc2[m][n] = __builtin_amdgcn_mfma_f32_16x16x32_f16(a[m], b[n], acc2[m][n], 0, 0, 0);
      }
    }
  }

  // ---------- elementwise epilogue (registers + streaming scores; no LDS needed) ----------
  // C/D layout (16x16x32): col = lane&15, row = (lane>>4)*4 + reg
  const int rbase = row0 + (wr << 6) + (fg << 2);
  const int cbase = col0 + (wc << 6) + fr;

  #pragma unroll
  for (int m = 0; m < 4; ++m) {
    #pragma unroll
    for (int reg = 0; reg < 4; ++reg) {
      const int rg = rbase + (m << 4) + reg;
      if (PASS == 1) {
        float v1 = 0.f, v2 = 0.f, cnp = 0.f;
        #pragma unroll
        for (int n = 0; n < 4; ++n) {
          const float scv = __builtin_nontemporal_load(&scores[(size_t)rg * NB + cbase + (n << 4)]);
          const bool nb = (scv <= 0.3f);
          v1 += nb ? __expf(acc1[m][n][reg]) : 0.f;
          v2 += nb ? __expf(acc2[m][n][reg]) : 0.f;
          cnp += (nb ? 1.f : 0.f) + ((scv > 0.5f) ? 256.f : 0.f);  // pack (n_neg, n_pos); per-block sum < 2^24
        }
        v1 = reduce16(v1); v2 = reduce16(v2); cnp = reduce16(cnp);
        if (fr == 0) {
          atomicAdd(&s_row[rg], v1);
          atomicAdd(&s_col[rg], v2);
          const float cp = floorf(cnp * (1.f / 256.f));   // unpack BEFORE atomic (global neg-sum would carry)
          atomicAdd(&cnt_neg[rg], cnp - 256.f * cp);
          atomicAdd(&cnt_pos[rg], cp);
        }
      } else {
        const float nlr = nl_row[rg];
        const float nlc = nl_col[rg];
        float v1 = 0.f, v2 = 0.f;
        #pragma unroll
        for (int n = 0; n < 4; ++n) {
          const float scv = __builtin_nontemporal_load(&scores[(size_t)rg * NB + cbase + (n << 4)]);
          const bool pb = (scv > 0.5f);
          const float z1 = nlr - acc1[m][n][reg];
          const float z2 = nlc - acc2[m][n][reg];
          // softplus(z) = max(z,0) + log1p(exp(-|z|)); exact at z = -inf (empty neg set)
          const float t1 = fmaxf(z1, 0.f) + __logf(1.f + __expf(-fabsf(z1)));
          const float t2 = fmaxf(z2, 0.f) + __logf(1.f + __expf(-fabsf(z2)));
          v1 += pb ? t1 : 0.f;
          v2 += pb ? t2 : 0.f;
        }
        v1 = reduce16(v1); v2 = reduce16(v2);
        if (fr == 0) {
          atomicAdd(&acc_i2t[rg], v1);
          atomicAdd(&acc_t2i[rg], v2);
        }
      }
    }
  }
}

// ---------- nl = log(sum_exp) ----------
__global__ __launch_bounds__(256) void mid_kernel(const float* __restrict__ s_row,
                                                  const float* __restrict__ s_col,
                                                  float* __restrict__ nl_row,
                                                  float* __restrict__ nl_col) {
  const int i = blockIdx.x * 256 + threadIdx.x;
  nl_row[i] = logf(s_row[i]);
  nl_col[i] = logf(s_col[i]);
}

// ---------- final scalar reduction ----------
__global__ __launch_bounds__(256) void final_kernel(const float* __restrict__ acc_i2t,
                                                    const float* __restrict__ acc_t2i,
                                                    const float* __restrict__ cnt_neg,
                                                    const float* __restrict__ cnt_pos,
                                                    float* __restrict__ out) {
  float t = 0.f;
  for (int i = threadIdx.x; i < NB; i += 256) {
    const float denom = (1.0f + cnt_neg[i]) * cnt_pos[i];
    t += 0.5f * (acc_i2t[i] + acc_t2i[i]) / denom;   // ALPHA = 0.5 on both terms
  }
  #pragma unroll
  for (int d = 1; d < 64; d <<= 1) t += __shfl_xor(t, d, 64);
  __shared__ float wsum[4];
  if ((threadIdx.x & 63) == 0) wsum[threadIdx.x >> 6] = t;
  __syncthreads();
  if (threadIdx.x == 0)
    out[0] = (wsum[0] + wsum[1] + wsum[2] + wsum[3]) * (1.0f / (float)NB);
}

extern "C" void kernel_launch(void* const* d_in, const int* in_sizes, int n_in,
                              void* d_out, int out_size, void* d_ws, size_t ws_size,
                              hipStream_t stream) {
  (void)in_sizes; (void)n_in; (void)out_size; (void)ws_size;
  const float* f_img  = (const float*)d_in[0];
  const float* f_txt  = (const float*)d_in[1];
  const float* scores = (const float*)d_in[2];

  char* ws = (char*)d_ws;
  f16* fi16 = (f16*)ws;                                   // 4 MiB
  f16* ft16 = (f16*)(ws + (size_t)(4 << 20));             // 4 MiB
  float* s_row   = (float*)(ws + (size_t)(8 << 20));      // 8 arrays x 32 KiB
  float* s_col   = s_row + NB;
  float* cnt_neg = s_row + 2 * NB;
  float* cnt_pos = s_row + 3 * NB;
  float* acc_i2t = s_row + 4 * NB;
  float* acc_t2i = s_row + 5 * NB;
  float* nl_row  = s_row + 6 * NB;
  float* nl_col  = s_row + 7 * NB;

  (void)hipMemsetAsync(s_row, 0, 6 * NB * sizeof(float), stream);
  hipLaunchKernelGGL(prep_kernel, dim3(4096), dim3(256), 0, stream, f_img, f_txt, fi16, ft16);
  hipLaunchKernelGGL(HIP_KERNEL_NAME(hloss_tile<1>), dim3(4096), dim3(256), 0, stream,
                     fi16, ft16, scores, s_row, s_col, cnt_neg, cnt_pos,
                     nl_row, nl_col, acc_i2t, acc_t2i);
  hipLaunchKernelGGL(mid_kernel, dim3(32), dim3(256), 0, stream, s_row, s_col, nl_row, nl_col);
  hipLaunchKernelGGL(HIP_KERNEL_NAME(hloss_tile<2>), dim3(4096), dim3(256), 0, stream,
                     fi16, ft16, scores, s_row, s_col, cnt_neg, cnt_pos,
                     nl_row, nl_col, acc_i2t, acc_t2i);
  hipLaunchKernelGGL(final_kernel, dim3(1), dim3(256), 0, stream,
                     acc_i2t, acc_t2i, cnt_neg, cnt_pos, (float*)d_out);
}